// Round 19
// baseline (344.122 us; speedup 1.0000x reference)
//
#include <hip/hip_runtime.h>
#include <hip/hip_bf16.h>
#include <math.h>

// Problem: S=128, B=16, D=H=512, O=256.
// Collapse 1: watch/sus are exactly s-independent -> [16,512] recurrence;
//             outs broadcasts [128,16,256].
// Collapse 2: recurrence is row-independent -> 16 independent b-recurrences.
// Pipeline (R18 + pre-split weights): split_all (one-time hi/lo bf16
// transpose of the 4 weight mats into ws, runtime ws_size-gated with exact
// R18 fallback) -> gemm_ps (B-frags loaded directly from global pre-split
// buffers; no B staging) -> softmax -> gemm_ps -> recurrence (R18 frozen:
// 256 WGs = 16b x 16parts, wave-local poll, 1.40 us/step) -> gemm_dual_ps
// -> sus_scan -> finalize.
// Epoch-in-data u64 (epoch<<32|f32 bits): 0xAA poison never matches epoch t;
// values deterministic -> stale/cross-replay matches are bit-identical/safe.
// GEMM numerics: split-bf16 (hi/lo, 3 mfma per pair, ~2^-16 rel err).

#define S_LEN 128
#define B_SZ  16
#define H_SZ  512
#define O_SZ  256
#define ROWS  (S_LEN * B_SZ)   // 2048

#define OUTS_ELEMS  (S_LEN * S_LEN * B_SZ * O_SZ)   // 67,108,864
#define WATCH_ELEMS (S_LEN * B_SZ * H_SZ)           // 1,048,576

// pre-split weight buffer offsets (bf16 elems), base at ws byte 13M
#define ATW_H 0
#define ATW_L 262144
#define INW_H 524288
#define INW_L 786432
#define SUSW_H 1048576
#define SUSW_L 1310720
#define OUTW_H 1572864
#define OUTW_L 1703936
#define SPLIT_ELEMS 1835008   // 3.5 MB

typedef float  f32x4  __attribute__((ext_vector_type(4)));
typedef __bf16 bf16x8 __attribute__((ext_vector_type(8)));

// ================= one-time weight split+transpose ==========================
// W[K][N] f32 -> Wh/Wl[N][512] bf16 (K always 512 here). 32x32 LDS tiles.
__global__ __launch_bounds__(256) void split_all(
    const float* __restrict__ aw, const float* __restrict__ iw,
    const float* __restrict__ sw, const float* __restrict__ ow,
    __bf16* __restrict__ base)
{
  __shared__ float tile[32][33];
  const int bid = blockIdx.x;
  const float* W; __bf16* Wh; __bf16* Wl; int N, kt, nt;
  if (bid < 256) {
    W = aw; Wh = base + ATW_H; Wl = base + ATW_L; N = 512;
    kt = (bid >> 4) << 5; nt = (bid & 15) << 5;
  } else if (bid < 512) {
    const int lo = bid - 256;
    W = iw; Wh = base + INW_H; Wl = base + INW_L; N = 512;
    kt = (lo >> 4) << 5; nt = (lo & 15) << 5;
  } else if (bid < 768) {
    const int lo = bid - 512;
    W = sw; Wh = base + SUSW_H; Wl = base + SUSW_L; N = 512;
    kt = (lo >> 4) << 5; nt = (lo & 15) << 5;
  } else {
    const int lo = bid - 768;
    W = ow; Wh = base + OUTW_H; Wl = base + OUTW_L; N = 256;
    kt = (lo >> 3) << 5; nt = (lo & 7) << 5;
  }
  const int tk = threadIdx.x & 31, tr = threadIdx.x >> 5;
  for (int r = tr; r < 32; r += 8)
    tile[r][tk] = W[(size_t)(kt + r) * N + nt + tk];
  __syncthreads();
  for (int c = tr; c < 32; c += 8) {
    const float v = tile[tk][c];               // k = kt+tk, col = nt+c
    const __bf16 h = (__bf16)v;
    Wh[(size_t)(nt + c) * 512 + kt + tk] = h;
    Wl[(size_t)(nt + c) * 512 + kt + tk] = (__bf16)(v - (float)h);
  }
}

// ================= GEMM with pre-split B (direct global frag loads) =========
struct alignas(16) ALds { __bf16 Ah[64][40]; __bf16 Al[64][40]; };

__device__ __forceinline__ void gemm_ps_body(
    const float* __restrict__ A,
    const __bf16* __restrict__ Bth, const __bf16* __restrict__ Btl,
    const float* __restrict__ bias0, const float* __restrict__ bias1,
    float* __restrict__ C, int N, int K, int bm, int bn, ALds& T)
{
  const int tid = threadIdx.x;
  const int w = tid >> 6, l = tid & 63;
  const int fr = l & 15, fg = l >> 4;
  f32x4 acc[4] = {{0,0,0,0},{0,0,0,0},{0,0,0,0},{0,0,0,0}};
  const int ar = tid >> 2, ak = (tid & 3) << 3;   // A staging: row, k8

  for (int k0 = 0; k0 < K; k0 += 32) {
    {
      const float* s = &A[(size_t)(bm + ar) * K + k0 + ak];
      const f32x4 v0 = *(const f32x4*)s, v1 = *(const f32x4*)(s + 4);
      const float vv[8] = {v0.x, v0.y, v0.z, v0.w, v1.x, v1.y, v1.z, v1.w};
      bf16x8 h, lo;
#pragma unroll
      for (int j = 0; j < 8; ++j) {
        const __bf16 hh = (__bf16)vv[j];
        h[j] = hh; lo[j] = (__bf16)(vv[j] - (float)hh);
      }
      *(bf16x8*)&T.Ah[ar][ak] = h;
      *(bf16x8*)&T.Al[ar][ak] = lo;
    }
    __syncthreads();
    const bf16x8 ah = *(const bf16x8*)&T.Ah[(w << 4) + fr][fg << 3];
    const bf16x8 al = *(const bf16x8*)&T.Al[(w << 4) + fr][fg << 3];
#pragma unroll
    for (int nr = 0; nr < 4; ++nr) {
      const int col = bn + (nr << 4) + fr;
      const bf16x8 bh = *(const bf16x8*)&Bth[(size_t)col * 512 + k0 + (fg << 3)];
      const bf16x8 bl = *(const bf16x8*)&Btl[(size_t)col * 512 + k0 + (fg << 3)];
      acc[nr] = __builtin_amdgcn_mfma_f32_16x16x32_bf16(ah, bh, acc[nr], 0, 0, 0);
      acc[nr] = __builtin_amdgcn_mfma_f32_16x16x32_bf16(al, bh, acc[nr], 0, 0, 0);
      acc[nr] = __builtin_amdgcn_mfma_f32_16x16x32_bf16(ah, bl, acc[nr], 0, 0, 0);
    }
    __syncthreads();
  }
#pragma unroll
  for (int nr = 0; nr < 4; ++nr) {
    const int gcol = bn + (nr << 4) + fr;
    float bb = bias0 ? bias0[gcol] : 0.f;
    if (bias1) bb += bias1[gcol];
#pragma unroll
    for (int r = 0; r < 4; ++r) {
      const int grow = bm + (w << 4) + (fg << 2) + r;
      C[(size_t)grow * N + gcol] = acc[nr][r] + bb;
    }
  }
}

__global__ __launch_bounds__(256) void gemm_ps(
    const float* __restrict__ A,
    const __bf16* __restrict__ Bth, const __bf16* __restrict__ Btl,
    const float* __restrict__ bias0, const float* __restrict__ bias1,
    float* __restrict__ C, int N, int K)
{
  __shared__ ALds T;
  gemm_ps_body(A, Bth, Btl, bias0, bias1, C, N, K,
               blockIdx.y << 6, blockIdx.x << 6, T);
}

__global__ __launch_bounds__(256) void gemm_dual_ps(
    const float* __restrict__ A,
    const __bf16* __restrict__ B1h, const __bf16* __restrict__ B1l,
    const float* __restrict__ b1, float* __restrict__ C1,
    const __bf16* __restrict__ B2h, const __bf16* __restrict__ B2l,
    const float* __restrict__ b2, float* __restrict__ C2)
{
  __shared__ ALds T;
  if (blockIdx.x < 8)
    gemm_ps_body(A, B1h, B1l, b1, nullptr, C1, 512, 512,
                 blockIdx.y << 6, blockIdx.x << 6, T);
  else
    gemm_ps_body(A, B2h, B2l, b2, nullptr, C2, 256, 512,
                 blockIdx.y << 6, (blockIdx.x - 8) << 6, T);
}

// ================= fallback GEMM (in-kernel split; exact R18) ===============
struct alignas(16) GemmLds {
  __bf16 Ah[64][40]; __bf16 Al[64][40];
  __bf16 Bh[64][40]; __bf16 Bl[64][40];
};

__device__ __forceinline__ void gemm_body(
    const float* __restrict__ A, const float* __restrict__ B,
    const float* __restrict__ bias0, const float* __restrict__ bias1,
    float* __restrict__ C, int N, int K, int bm, int bn, GemmLds& T)
{
  const int tid = threadIdx.x;
  const int w = tid >> 6, l = tid & 63;
  const int fr = l & 15, fg = l >> 4;
  f32x4 acc[4] = {{0,0,0,0},{0,0,0,0},{0,0,0,0},{0,0,0,0}};
  const int ar = tid >> 2, ak = (tid & 3) << 3;
  const int bk = tid >> 3, bc = (tid & 7) << 3;

  for (int k0 = 0; k0 < K; k0 += 32) {
    {
      const float* s = &A[(size_t)(bm + ar) * K + k0 + ak];
      const f32x4 v0 = *(const f32x4*)s, v1 = *(const f32x4*)(s + 4);
      const float vv[8] = {v0.x, v0.y, v0.z, v0.w, v1.x, v1.y, v1.z, v1.w};
      bf16x8 h, lo;
#pragma unroll
      for (int j = 0; j < 8; ++j) {
        const __bf16 hh = (__bf16)vv[j];
        h[j] = hh; lo[j] = (__bf16)(vv[j] - (float)hh);
      }
      *(bf16x8*)&T.Ah[ar][ak] = h;
      *(bf16x8*)&T.Al[ar][ak] = lo;
    }
    {
      const float* s = &B[(size_t)(k0 + bk) * N + bn + bc];
      const f32x4 v0 = *(const f32x4*)s, v1 = *(const f32x4*)(s + 4);
      const float vv[8] = {v0.x, v0.y, v0.z, v0.w, v1.x, v1.y, v1.z, v1.w};
#pragma unroll
      for (int j = 0; j < 8; ++j) {
        const __bf16 hh = (__bf16)vv[j];
        T.Bh[bc + j][bk] = hh;
        T.Bl[bc + j][bk] = (__bf16)(vv[j] - (float)hh);
      }
    }
    __syncthreads();
    const bf16x8 ah = *(const bf16x8*)&T.Ah[(w << 4) + fr][fg << 3];
    const bf16x8 al = *(const bf16x8*)&T.Al[(w << 4) + fr][fg << 3];
#pragma unroll
    for (int nr = 0; nr < 4; ++nr) {
      const bf16x8 bh = *(const bf16x8*)&T.Bh[(nr << 4) + fr][fg << 3];
      const bf16x8 bl = *(const bf16x8*)&T.Bl[(nr << 4) + fr][fg << 3];
      acc[nr] = __builtin_amdgcn_mfma_f32_16x16x32_bf16(ah, bh, acc[nr], 0, 0, 0);
      acc[nr] = __builtin_amdgcn_mfma_f32_16x16x32_bf16(al, bh, acc[nr], 0, 0, 0);
      acc[nr] = __builtin_amdgcn_mfma_f32_16x16x32_bf16(ah, bl, acc[nr], 0, 0, 0);
    }
    __syncthreads();
  }
#pragma unroll
  for (int nr = 0; nr < 4; ++nr) {
    const int gcol = bn + (nr << 4) + fr;
    float bb = bias0 ? bias0[gcol] : 0.f;
    if (bias1) bb += bias1[gcol];
#pragma unroll
    for (int r = 0; r < 4; ++r) {
      const int grow = bm + (w << 4) + (fg << 2) + r;
      C[(size_t)grow * N + gcol] = acc[nr][r] + bb;
    }
  }
}

__global__ __launch_bounds__(256) void gemm_mfma(
    const float* __restrict__ A, const float* __restrict__ B,
    const float* __restrict__ bias0, const float* __restrict__ bias1,
    float* __restrict__ C, int N, int K)
{
  __shared__ GemmLds T;
  gemm_body(A, B, bias0, bias1, C, N, K, blockIdx.y << 6, blockIdx.x << 6, T);
}

__global__ __launch_bounds__(256) void gemm_dual_mfma(
    const float* __restrict__ A,
    const float* __restrict__ B1, const float* __restrict__ b1, float* __restrict__ C1,
    const float* __restrict__ B2, const float* __restrict__ b2, float* __restrict__ C2)
{
  __shared__ GemmLds T;
  if (blockIdx.x < 8)
    gemm_body(A, B1, b1, nullptr, C1, 512, 512, blockIdx.y << 6, blockIdx.x << 6, T);
  else
    gemm_body(A, B2, b2, nullptr, C2, 256, 512, blockIdx.y << 6, (blockIdx.x - 8) << 6, T);
}

// ---------------- softmax over H then gate by x (in-place on logits) --------
__global__ __launch_bounds__(64) void softmax_gate(float* __restrict__ lg,
                                                   const float* __restrict__ x)
{
  const int r = blockIdx.x;      // 0..2047
  const int lane = threadIdx.x;  // 0..63
  float v[8];
  float m = -1e30f;
#pragma unroll
  for (int i = 0; i < 8; ++i) {
    v[i] = lg[(r << 9) + (i << 6) + lane];
    m = fmaxf(m, v[i]);
  }
#pragma unroll
  for (int off = 32; off > 0; off >>= 1) m = fmaxf(m, __shfl_xor(m, off, 64));
  float s = 0.f;
#pragma unroll
  for (int i = 0; i < 8; ++i) { v[i] = expf(v[i] - m); s += v[i]; }
#pragma unroll
  for (int off = 32; off > 0; off >>= 1) s += __shfl_xor(s, off, 64);
  const float inv = 1.0f / s;
#pragma unroll
  for (int i = 0; i < 8; ++i) {
    const int idx = (r << 9) + (i << 6) + lane;
    lg[idx] = v[i] * inv * x[idx];
  }
}

// ---------------- recurrence (R18 frozen): 256 WGs = 16 b x 16 parts --------
__global__ __launch_bounds__(256, 1) void recurrence(
    const float* __restrict__ cbuf,          // [128][16][512]
    const float* __restrict__ insw,          // [512][512]
    float* __restrict__ wall,                // [128][16][512]
    unsigned long long* __restrict__ pz)     // [16][16][512] u64 ring
{
  __shared__ float wsm[H_SZ];
  __shared__ float red[2][4][32];

  const int wg  = blockIdx.x;
  const int b   = wg & 15;
  const int p   = wg >> 4;           // 0..15
  const int tid = threadIdx.x;
  const int l   = tid & 63;
  const int kq  = tid >> 6;          // wave 0..3
  const int colL = l & 31;
  const int h    = l >> 5;
  const int c   = (p << 5) + colL;
  const int kb  = (kq << 7) + (h << 6);

  f32x4 wr[16];
#pragma unroll
  for (int j = 0; j < 16; ++j) {
    wr[j].x = insw[((kb + 4 * j + 0) << 9) + c];
    wr[j].y = insw[((kb + 4 * j + 1) << 9) + c];
    wr[j].z = insw[((kb + 4 * j + 2) << 9) + c];
    wr[j].w = insw[((kb + 4 * j + 3) << 9) + c];
  }

  if (tid < 32) {
    const float v = tanhf(cbuf[(b << 9) + c]);
    wall[(b << 9) + c] = v;
    const unsigned long long pk =
        (1ULL << 32) | (unsigned long long)__float_as_uint(v);
    __hip_atomic_store(&pz[(b << 9) + c], pk, __ATOMIC_RELAXED,
                       __HIP_MEMORY_SCOPE_AGENT);
  }

  for (int t = 1; t < S_LEN; ++t) {
    const float cv = cbuf[(t << 13) + (b << 9) + c];

    const unsigned long long* src =
        pz + (((t - 1) & 15) << 13) + (b << 9);
    unsigned long long v0, v1;
    for (;;) {
      v0 = __hip_atomic_load(&src[2 * tid], __ATOMIC_RELAXED,
                             __HIP_MEMORY_SCOPE_AGENT);
      v1 = __hip_atomic_load(&src[2 * tid + 1], __ATOMIC_RELAXED,
                             __HIP_MEMORY_SCOPE_AGENT);
      const bool ok = ((unsigned)(v0 >> 32) == (unsigned)t) &
                      ((unsigned)(v1 >> 32) == (unsigned)t);
      if (__ballot(ok) == ~0ULL) break;
    }
    wsm[2 * tid]     = __uint_as_float((unsigned)v0);
    wsm[2 * tid + 1] = __uint_as_float((unsigned)v1);
    asm volatile("s_waitcnt lgkmcnt(0)" ::: "memory");
    __builtin_amdgcn_sched_barrier(0);

    float a0 = 0.f, a1 = 0.f, a2 = 0.f, a3 = 0.f;
#pragma unroll
    for (int j = 0; j < 16; ++j) {
      const f32x4 wv = *(const f32x4*)&wsm[kb + (j << 2)];
      a0 = fmaf(wr[j].x, wv.x, a0);
      a1 = fmaf(wr[j].y, wv.y, a1);
      a2 = fmaf(wr[j].z, wv.z, a2);
      a3 = fmaf(wr[j].w, wv.w, a3);
    }
    float z = (a0 + a1) + (a2 + a3);
    z += __shfl_xor(z, 32, 64);
    if (l < 32) red[t & 1][kq][colL] = z;
    __syncthreads();
    if (tid < 32) {
      const float y = red[t & 1][0][tid] + red[t & 1][1][tid] +
                      red[t & 1][2][tid] + red[t & 1][3][tid];
      const float v = tanhf(cv + y);
      wall[(t << 13) + (b << 9) + c] = v;
      const unsigned long long pk =
          ((unsigned long long)(unsigned)(t + 1) << 32) |
          (unsigned long long)__float_as_uint(v);
      __hip_atomic_store(&pz[((t & 15) << 13) + (b << 9) + c], pk,
                         __ATOMIC_RELAXED, __HIP_MEMORY_SCOPE_AGENT);
    }
  }
}

// ---------------- sus scan (prefetch depth 4) -------------------------------
__global__ __launch_bounds__(256) void sus_scan(
    const float* __restrict__ M, float* __restrict__ s_small)
{
  const int gid = blockIdx.x * blockDim.x + threadIdx.x;  // 8192
  float s = 0.f;
  float n0 = M[gid];
  float n1 = M[(1 << 13) + gid];
  float n2 = M[(2 << 13) + gid];
  float n3 = M[(3 << 13) + gid];
  for (int t = 0; t < S_LEN - 4; ++t) {
    const float cur = n0;
    n0 = n1; n1 = n2; n2 = n3;
    n3 = M[((t + 4) << 13) + gid];
    s = tanhf(cur + s);
  }
  s = tanhf(n0 + s); s = tanhf(n1 + s); s = tanhf(n2 + s); s = tanhf(n3 + s);
  s_small[gid] = s;
}

// ---------------- finalize: outs + watch + sus broadcast --------------------
__global__ __launch_bounds__(256) void finalize(
    const f32x4* __restrict__ os4, f32x4* __restrict__ outs4,
    const f32x4* __restrict__ w127, const f32x4* __restrict__ s4,
    f32x4* __restrict__ watch_out, f32x4* __restrict__ sus_out)
{
  const int gid = blockIdx.x * blockDim.x + threadIdx.x;
  const int stride = gridDim.x * blockDim.x;
  for (int i = gid; i < (1 << 24); i += stride) {
    const int o4 = i & 63;
    const int b  = (i >> 6) & 15;
    const int t  = i >> 17;
    __builtin_nontemporal_store(os4[(((t << 4) + b) << 6) + o4], &outs4[i]);
  }
  if (gid < (1 << 18)) {
    const int src = gid & 2047;
    __builtin_nontemporal_store(w127[src], &watch_out[gid]);
    __builtin_nontemporal_store(s4[src], &sus_out[gid]);
  }
}

extern "C" void kernel_launch(void* const* d_in, const int* in_sizes, int n_in,
                              void* d_out, int out_size, void* d_ws, size_t ws_size,
                              hipStream_t stream)
{
  const float* x      = (const float*)d_in[0];
  const float* attn_w = (const float*)d_in[1];
  const float* attn_b = (const float*)d_in[2];
  const float* in_w   = (const float*)d_in[3];
  const float* in_b   = (const float*)d_in[4];
  const float* ins_w  = (const float*)d_in[5];
  const float* ins_b  = (const float*)d_in[6];
  const float* sus_w  = (const float*)d_in[7];
  const float* sus_b  = (const float*)d_in[8];
  const float* out_w  = (const float*)d_in[9];
  const float* out_b  = (const float*)d_in[10];

  // ws (bytes): cbuf [0,4M) | wall [4M,8M) | tmp->mbuf [8M,12M) | pz [12M,13M)
  // | pre-split weights [13M,16.5M) if ws allows. obuf/s_small reuse cbuf.
  float* ws    = (float*)d_ws;
  float* cbuf  = ws;
  float* wallb = ws + (1 << 20);
  float* tmp   = ws + (2 << 20);
  float* mbuf  = tmp;
  unsigned long long* pz = (unsigned long long*)(ws + (3 << 20));
  __bf16* wsp = (__bf16*)((char*)d_ws + ((size_t)13 << 20));
  float* obuf    = ws;
  float* s_small = ws + (1 << 19);

  const bool psok = ws_size >= (((size_t)13 << 20) + SPLIT_ELEMS * 2);

  float* outp   = (float*)d_out;
  float* watchp = outp + OUTS_ELEMS;
  float* susp   = watchp + WATCH_ELEMS;

  const dim3 blk(256);
  if (psok) {
    // one-time (per call) weight split+transpose (3.5 MB)
    split_all<<<dim3(896), blk, 0, stream>>>(attn_w, in_w, sus_w, out_w, wsp);
    gemm_ps<<<dim3(8, 32), blk, 0, stream>>>(x, wsp + ATW_H, wsp + ATW_L,
                                             attn_b, nullptr, tmp, 512, 512);
    softmax_gate<<<dim3(2048), dim3(64), 0, stream>>>(tmp, x);
    gemm_ps<<<dim3(8, 32), blk, 0, stream>>>(tmp, wsp + INW_H, wsp + INW_L,
                                             in_b, ins_b, cbuf, 512, 512);
    recurrence<<<dim3(256), blk, 0, stream>>>(cbuf, ins_w, wallb, pz);
    gemm_dual_ps<<<dim3(12, 32), blk, 0, stream>>>(
        wallb, wsp + SUSW_H, wsp + SUSW_L, sus_b, mbuf,
        wsp + OUTW_H, wsp + OUTW_L, out_b, obuf);
  } else {
    // exact R18 fallback
    gemm_mfma<<<dim3(8, 32), blk, 0, stream>>>(x, attn_w, attn_b, nullptr, tmp, 512, 512);
    softmax_gate<<<dim3(2048), dim3(64), 0, stream>>>(tmp, x);
    gemm_mfma<<<dim3(8, 32), blk, 0, stream>>>(tmp, in_w, in_b, ins_b, cbuf, 512, 512);
    recurrence<<<dim3(256), blk, 0, stream>>>(cbuf, ins_w, wallb, pz);
    gemm_dual_mfma<<<dim3(12, 32), blk, 0, stream>>>(wallb, sus_w, sus_b, mbuf,
                                                     out_w, out_b, obuf);
  }
  sus_scan<<<dim3(32), blk, 0, stream>>>(mbuf, s_small);
  finalize<<<dim3(4096), blk, 0, stream>>>(
      (const f32x4*)obuf, (f32x4*)d_out,
      (const f32x4*)(wallb + (127 << 13)), (const f32x4*)s_small,
      (f32x4*)watchp, (f32x4*)susp);
}

// Round 20
// 327.896 us; speedup vs baseline: 1.0495x; 1.0495x over previous
//
#include <hip/hip_runtime.h>
#include <hip/hip_bf16.h>
#include <math.h>

// Problem: S=128, B=16, D=H=512, O=256.
// Collapse 1: watch/sus are exactly s-independent -> [16,512] recurrence;
//             outs broadcasts [128,16,256].
// Collapse 2: recurrence is row-independent -> 16 independent b-recurrences.
// == R18 EXACT (session best, 328.0 us) ==
// Pipeline: MFMA prologue -> recurrence (256 WGs = 16b x 16parts, wave-local
// poll, 1.40 us/step) -> dual GEMM -> sus_scan -> finalize.
// Recurrence sync: thread tid polls pz[2tid,2tid+1] (exactly its wave's FMA
// k-range), wave-private wsm + lgkmcnt(0)+sched_barrier (rule #18), ONE
// syncthreads/step (parity-dbuf red). K-reduce: shfl_xor(32) + 4-wave LDS
// reduce; publishers tid<32 (fan-in 1).
// Epoch-in-data u64 (epoch<<32|f32 bits): 0xAA poison never matches epoch t;
// values deterministic -> stale/cross-replay matches are bit-identical/safe.
// GEMMs: MFMA split-bf16 (hi/lo, 3 mfma_16x16x32 per pair, ~2^-16 rel err).

#define S_LEN 128
#define B_SZ  16
#define H_SZ  512
#define O_SZ  256
#define ROWS  (S_LEN * B_SZ)   // 2048

#define OUTS_ELEMS  (S_LEN * S_LEN * B_SZ * O_SZ)   // 67,108,864
#define WATCH_ELEMS (S_LEN * B_SZ * H_SZ)           // 1,048,576

typedef float  f32x4  __attribute__((ext_vector_type(4)));
typedef __bf16 bf16x8 __attribute__((ext_vector_type(8)));

// ================= MFMA split-bf16 GEMM =====================================
struct alignas(16) GemmLds {
  __bf16 Ah[64][40]; __bf16 Al[64][40];
  __bf16 Bh[64][40]; __bf16 Bl[64][40];
};

__device__ __forceinline__ void gemm_body(
    const float* __restrict__ A, const float* __restrict__ B,
    const float* __restrict__ bias0, const float* __restrict__ bias1,
    float* __restrict__ C, int N, int K, int bm, int bn, GemmLds& T)
{
  const int tid = threadIdx.x;
  const int w = tid >> 6, l = tid & 63;
  const int fr = l & 15, fg = l >> 4;
  f32x4 acc[4] = {{0,0,0,0},{0,0,0,0},{0,0,0,0},{0,0,0,0}};
  const int ar = tid >> 2, ak = (tid & 3) << 3;   // A staging: row, k8
  const int bk = tid >> 3, bc = (tid & 7) << 3;   // B staging: k, col8

  for (int k0 = 0; k0 < K; k0 += 32) {
    {
      const float* s = &A[(size_t)(bm + ar) * K + k0 + ak];
      const f32x4 v0 = *(const f32x4*)s, v1 = *(const f32x4*)(s + 4);
      const float vv[8] = {v0.x, v0.y, v0.z, v0.w, v1.x, v1.y, v1.z, v1.w};
      bf16x8 h, lo;
#pragma unroll
      for (int j = 0; j < 8; ++j) {
        const __bf16 hh = (__bf16)vv[j];
        h[j] = hh; lo[j] = (__bf16)(vv[j] - (float)hh);
      }
      *(bf16x8*)&T.Ah[ar][ak] = h;
      *(bf16x8*)&T.Al[ar][ak] = lo;
    }
    {
      const float* s = &B[(size_t)(k0 + bk) * N + bn + bc];
      const f32x4 v0 = *(const f32x4*)s, v1 = *(const f32x4*)(s + 4);
      const float vv[8] = {v0.x, v0.y, v0.z, v0.w, v1.x, v1.y, v1.z, v1.w};
#pragma unroll
      for (int j = 0; j < 8; ++j) {
        const __bf16 hh = (__bf16)vv[j];
        T.Bh[bc + j][bk] = hh;
        T.Bl[bc + j][bk] = (__bf16)(vv[j] - (float)hh);
      }
    }
    __syncthreads();
    const bf16x8 ah = *(const bf16x8*)&T.Ah[(w << 4) + fr][fg << 3];
    const bf16x8 al = *(const bf16x8*)&T.Al[(w << 4) + fr][fg << 3];
#pragma unroll
    for (int nr = 0; nr < 4; ++nr) {
      const bf16x8 bh = *(const bf16x8*)&T.Bh[(nr << 4) + fr][fg << 3];
      const bf16x8 bl = *(const bf16x8*)&T.Bl[(nr << 4) + fr][fg << 3];
      acc[nr] = __builtin_amdgcn_mfma_f32_16x16x32_bf16(ah, bh, acc[nr], 0, 0, 0);
      acc[nr] = __builtin_amdgcn_mfma_f32_16x16x32_bf16(al, bh, acc[nr], 0, 0, 0);
      acc[nr] = __builtin_amdgcn_mfma_f32_16x16x32_bf16(ah, bl, acc[nr], 0, 0, 0);
    }
    __syncthreads();
  }
#pragma unroll
  for (int nr = 0; nr < 4; ++nr) {
    const int gcol = bn + (nr << 4) + fr;
    float bb = bias0 ? bias0[gcol] : 0.f;
    if (bias1) bb += bias1[gcol];
#pragma unroll
    for (int r = 0; r < 4; ++r) {
      const int grow = bm + (w << 4) + (fg << 2) + r;
      C[(size_t)grow * N + gcol] = acc[nr][r] + bb;
    }
  }
}

__global__ __launch_bounds__(256) void gemm_mfma(
    const float* __restrict__ A, const float* __restrict__ B,
    const float* __restrict__ bias0, const float* __restrict__ bias1,
    float* __restrict__ C, int N, int K)
{
  __shared__ GemmLds T;
  gemm_body(A, B, bias0, bias1, C, N, K, blockIdx.y << 6, blockIdx.x << 6, T);
}

__global__ __launch_bounds__(256) void gemm_dual_mfma(
    const float* __restrict__ A,
    const float* __restrict__ B1, const float* __restrict__ b1, float* __restrict__ C1,
    const float* __restrict__ B2, const float* __restrict__ b2, float* __restrict__ C2)
{
  __shared__ GemmLds T;
  if (blockIdx.x < 8)
    gemm_body(A, B1, b1, nullptr, C1, 512, 512, blockIdx.y << 6, blockIdx.x << 6, T);
  else
    gemm_body(A, B2, b2, nullptr, C2, 256, 512, blockIdx.y << 6, (blockIdx.x - 8) << 6, T);
}

// ---------------- softmax over H then gate by x (in-place on logits) --------
__global__ __launch_bounds__(64) void softmax_gate(float* __restrict__ lg,
                                                   const float* __restrict__ x)
{
  const int r = blockIdx.x;      // 0..2047
  const int lane = threadIdx.x;  // 0..63
  float v[8];
  float m = -1e30f;
#pragma unroll
  for (int i = 0; i < 8; ++i) {
    v[i] = lg[(r << 9) + (i << 6) + lane];
    m = fmaxf(m, v[i]);
  }
#pragma unroll
  for (int off = 32; off > 0; off >>= 1) m = fmaxf(m, __shfl_xor(m, off, 64));
  float s = 0.f;
#pragma unroll
  for (int i = 0; i < 8; ++i) { v[i] = expf(v[i] - m); s += v[i]; }
#pragma unroll
  for (int off = 32; off > 0; off >>= 1) s += __shfl_xor(s, off, 64);
  const float inv = 1.0f / s;
#pragma unroll
  for (int i = 0; i < 8; ++i) {
    const int idx = (r << 9) + (i << 6) + lane;
    lg[idx] = v[i] * inv * x[idx];
  }
}

// ---------------- recurrence: 256 WGs = 16 b x 16 parts (32 cols) -----------
// Wave kq owns K-range [128kq,128kq+128); lane l: col = 32p + (l&31),
// k-half h = l>>5 -> 64 weights/thread. Thread tid polls pz[2tid,2tid+1]
// (exactly its wave's k-range). K-reduce: shfl_xor(32) then 4-wave LDS
// reduce; publishers tid<32 (fan-in 1).
__global__ __launch_bounds__(256, 1) void recurrence(
    const float* __restrict__ cbuf,          // [128][16][512]
    const float* __restrict__ insw,          // [512][512]
    float* __restrict__ wall,                // [128][16][512]
    unsigned long long* __restrict__ pz)     // [16][16][512] u64 ring
{
  __shared__ float wsm[H_SZ];        // wave-private slices (wave kq: [128kq,+128))
  __shared__ float red[2][4][32];    // parity-dbuf cross-wave reduce

  const int wg  = blockIdx.x;
  const int b   = wg & 15;
  const int p   = wg >> 4;           // 0..15
  const int tid = threadIdx.x;
  const int l   = tid & 63;
  const int kq  = tid >> 6;          // wave 0..3
  const int colL = l & 31;
  const int h    = l >> 5;           // k-half within wave
  const int c   = (p << 5) + colL;   // owned col
  const int kb  = (kq << 7) + (h << 6);   // K base (64 k's)

  // weights: 64 f32/thread (L2 restream 64KB/step; R18-measured optimal)
  f32x4 wr[16];
#pragma unroll
  for (int j = 0; j < 16; ++j) {
    wr[j].x = insw[((kb + 4 * j + 0) << 9) + c];
    wr[j].y = insw[((kb + 4 * j + 1) << 9) + c];
    wr[j].z = insw[((kb + 4 * j + 2) << 9) + c];
    wr[j].w = insw[((kb + 4 * j + 3) << 9) + c];
  }

  // t = 0: publish w0 = tanh(c0) with epoch 1 in slot 0 (own 32 cols)
  if (tid < 32) {
    const float v = tanhf(cbuf[(b << 9) + c]);
    wall[(b << 9) + c] = v;
    const unsigned long long pk =
        (1ULL << 32) | (unsigned long long)__float_as_uint(v);
    __hip_atomic_store(&pz[(b << 9) + c], pk, __ATOMIC_RELAXED,
                       __HIP_MEMORY_SCOPE_AGENT);
  }

  for (int t = 1; t < S_LEN; ++t) {
    // prefetch c_t (only publishers use it)
    const float cv = cbuf[(t << 13) + (b << 9) + c];

    // wave-local poll: this wave's 64 lanes cover exactly [128kq,128kq+128)
    const unsigned long long* src =
        pz + (((t - 1) & 15) << 13) + (b << 9);
    unsigned long long v0, v1;
    for (;;) {
      v0 = __hip_atomic_load(&src[2 * tid], __ATOMIC_RELAXED,
                             __HIP_MEMORY_SCOPE_AGENT);
      v1 = __hip_atomic_load(&src[2 * tid + 1], __ATOMIC_RELAXED,
                             __HIP_MEMORY_SCOPE_AGENT);
      const bool ok = ((unsigned)(v0 >> 32) == (unsigned)t) &
                      ((unsigned)(v1 >> 32) == (unsigned)t);
      if (__ballot(ok) == ~0ULL) break;          // wave-local exit
    }
    // wave-private forwarding (only this wave reads this wsm range)
    wsm[2 * tid]     = __uint_as_float((unsigned)v0);
    wsm[2 * tid + 1] = __uint_as_float((unsigned)v1);
    asm volatile("s_waitcnt lgkmcnt(0)" ::: "memory");
    __builtin_amdgcn_sched_barrier(0);           // rule #18

    // partial dot over this lane's 64-k slice (reads: 2 b128 addrs/wave)
    float a0 = 0.f, a1 = 0.f, a2 = 0.f, a3 = 0.f;
#pragma unroll
    for (int j = 0; j < 16; ++j) {
      const f32x4 wv = *(const f32x4*)&wsm[kb + (j << 2)];
      a0 = fmaf(wr[j].x, wv.x, a0);
      a1 = fmaf(wr[j].y, wv.y, a1);
      a2 = fmaf(wr[j].z, wv.z, a2);
      a3 = fmaf(wr[j].w, wv.w, a3);
    }
    float z = (a0 + a1) + (a2 + a3);
    z += __shfl_xor(z, 32, 64);                  // add partner k-half
    if (l < 32) red[t & 1][kq][colL] = z;
    __syncthreads();                             // the ONE barrier per step
    if (tid < 32) {
      const float y = red[t & 1][0][tid] + red[t & 1][1][tid] +
                      red[t & 1][2][tid] + red[t & 1][3][tid];
      const float v = tanhf(cv + y);
      wall[(t << 13) + (b << 9) + c] = v;
      const unsigned long long pk =
          ((unsigned long long)(unsigned)(t + 1) << 32) |
          (unsigned long long)__float_as_uint(v);
      __hip_atomic_store(&pz[((t & 15) << 13) + (b << 9) + c], pk,
                         __ATOMIC_RELAXED, __HIP_MEMORY_SCOPE_AGENT);
    }
  }
}

// ---------------- sus scan (prefetch depth 4) -------------------------------
__global__ __launch_bounds__(256) void sus_scan(
    const float* __restrict__ M, float* __restrict__ s_small)
{
  const int gid = blockIdx.x * blockDim.x + threadIdx.x;  // 8192
  float s = 0.f;
  float n0 = M[gid];
  float n1 = M[(1 << 13) + gid];
  float n2 = M[(2 << 13) + gid];
  float n3 = M[(3 << 13) + gid];
  for (int t = 0; t < S_LEN - 4; ++t) {
    const float cur = n0;
    n0 = n1; n1 = n2; n2 = n3;
    n3 = M[((t + 4) << 13) + gid];
    s = tanhf(cur + s);
  }
  s = tanhf(n0 + s); s = tanhf(n1 + s); s = tanhf(n2 + s); s = tanhf(n3 + s);
  s_small[gid] = s;
}

// ---------------- finalize: outs + watch + sus broadcast --------------------
__global__ __launch_bounds__(256) void finalize(
    const f32x4* __restrict__ os4, f32x4* __restrict__ outs4,
    const f32x4* __restrict__ w127, const f32x4* __restrict__ s4,
    f32x4* __restrict__ watch_out, f32x4* __restrict__ sus_out)
{
  const int gid = blockIdx.x * blockDim.x + threadIdx.x;
  const int stride = gridDim.x * blockDim.x;
  for (int i = gid; i < (1 << 24); i += stride) {
    const int o4 = i & 63;
    const int b  = (i >> 6) & 15;
    const int t  = i >> 17;
    __builtin_nontemporal_store(os4[(((t << 4) + b) << 6) + o4], &outs4[i]);
  }
  if (gid < (1 << 18)) {
    const int src = gid & 2047;
    __builtin_nontemporal_store(w127[src], &watch_out[gid]);
    __builtin_nontemporal_store(s4[src], &sus_out[gid]);
  }
}

extern "C" void kernel_launch(void* const* d_in, const int* in_sizes, int n_in,
                              void* d_out, int out_size, void* d_ws, size_t ws_size,
                              hipStream_t stream)
{
  const float* x      = (const float*)d_in[0];
  const float* attn_w = (const float*)d_in[1];
  const float* attn_b = (const float*)d_in[2];
  const float* in_w   = (const float*)d_in[3];
  const float* in_b   = (const float*)d_in[4];
  const float* ins_w  = (const float*)d_in[5];
  const float* ins_b  = (const float*)d_in[6];
  const float* sus_w  = (const float*)d_in[7];
  const float* sus_b  = (const float*)d_in[8];
  const float* out_w  = (const float*)d_in[9];
  const float* out_b  = (const float*)d_in[10];

  // ws (bytes): cbuf [0,4M) | wall [4M,8M) | tmp->mbuf [8M,12M) | pz [12M,13M)
  // after recurrence, cbuf region reused: obuf [0,2M), s_small [2M,2M+32K)
  float* ws    = (float*)d_ws;
  float* cbuf  = ws;
  float* wallb = ws + (1 << 20);
  float* tmp   = ws + (2 << 20);
  float* mbuf  = tmp;
  unsigned long long* pz = (unsigned long long*)(ws + (3 << 20));
  float* obuf    = ws;
  float* s_small = ws + (1 << 19);

  float* outp   = (float*)d_out;
  float* watchp = outp + OUTS_ELEMS;
  float* susp   = watchp + WATCH_ELEMS;

  const dim3 blk(256);
  // logits = X @ attn_w + attn_b -> tmp   (MFMA split-bf16)
  gemm_mfma<<<dim3(8, 32), blk, 0, stream>>>(x, attn_w, attn_b, nullptr, tmp, 512, 512);
  // R = softmax(logits) * X   (in place on tmp)
  softmax_gate<<<dim3(2048), dim3(64), 0, stream>>>(tmp, x);
  // c = R @ in_w + in_b + ins_b -> cbuf
  gemm_mfma<<<dim3(8, 32), blk, 0, stream>>>(tmp, in_w, in_b, ins_b, cbuf, 512, 512);
  // sequential recurrence (no memset — epoch scheme replay-safe)
  recurrence<<<dim3(256), blk, 0, stream>>>(cbuf, ins_w, wallb, pz);
  // M = wall @ sus_w + sus_b -> mbuf ; out_small = wall @ out_w + out_b -> obuf
  gemm_dual_mfma<<<dim3(12, 32), blk, 0, stream>>>(wallb, sus_w, sus_b, mbuf,
                                                   out_w, out_b, obuf);
  // elementwise sus scan -> s_small
  sus_scan<<<dim3(32), blk, 0, stream>>>(mbuf, s_small);
  // outs broadcast (268 MB) + watch/sus broadcast (8 MB)
  finalize<<<dim3(4096), blk, 0, stream>>>(
      (const f32x4*)obuf, (f32x4*)d_out,
      (const f32x4*)(wallb + (127 << 13)), (const f32x4*)s_small,
      (f32x4*)watchp, (f32x4*)susp);
}